// Round 7
// baseline (201.218 us; speedup 1.0000x reference)
//
#include <hip/hip_runtime.h>
#include <math.h>

#define NCAT  5
#define BATCH 64
#define ELEMS 196608          // C*H*W = 3*256*256
#define EPSV  1e-6f

// native 4-float vector (works with __builtin_nontemporal_load)
typedef float v4f __attribute__((ext_vector_type(4)));

// ---- pass 1 geometry: 4 KB window per block, 16 waves (4 slices x 4 chunks)
#define WIN1   1024            // floats per block window (4 KB)
#define NBLK1  (ELEMS / WIN1)  // 192 blocks
#define TPB1   1024            // 16 waves; ws = wave&3 (slice), bc = wave>>2
#define CHUNK1 16              // batches per wave
#define GRP1   8               // batches in flight per wave

// ---- pass 2 geometry (streaming over clean/restored/s) ----
#define NSLAB  12              // slabs per batch (64 KB/array/block)
#define SLABSZ (ELEMS / NSLAB) // 16384 positions per slab
#define NBLK2  (BATCH * NSLAB) // 768 blocks

// d_ws layout (floats):
//   s_buf [NCAT][ELEMS]  @ 0
//   p1    [NCAT][NBLK1]  @ WS_P1   (per-cat un sums)
//   p2    [2][NBLK2]     @ WS_P2   (row0 = scaled sums, row1 = abs sums)
//   cnt   (1 uint)       @ WS_CNT  (pass2 completion counter, zeroed by pass1)
#define WS_S   0
#define WS_P1  (NCAT * ELEMS)
#define WS_P2  (WS_P1 + NCAT * NBLK1)
#define WS_CNT (WS_P2 + 2 * NBLK2)

static __device__ __forceinline__ v4f vfma(float m, v4f a, v4f b) {
    v4f r;
    r.x = fmaf(m, a.x, b.x);
    r.y = fmaf(m, a.y, b.y);
    r.z = fmaf(m, a.z, b.z);
    r.w = fmaf(m, a.w, b.w);
    return r;
}

// ---------------------------------------------------------------------------
// Pass 1: un_sum[cat][pos]; block sweeps a 4 KB window across all 64 batches
// (4 slice-waves in lockstep -> 4 KB DRAM runs), batch dim split over 4
// chunk-waves merged via LDS. Emits s = 1/(un_sum*inv+eps) and per-cat sums.
// ---------------------------------------------------------------------------
__global__ __launch_bounds__(TPB1) void pass1_kernel(
    const float* __restrict__ un,
    const int*   __restrict__ de_id,
    float*       __restrict__ s_buf,
    float*       __restrict__ p1,
    unsigned*    __restrict__ cnt)
{
    __shared__ int   sh_de[BATCH];
    __shared__ float sh_inv[NCAT];
    __shared__ v4f   sbuf[2][4][NCAT][64];   // [slot][slice][cat][lane] 40 KB
    __shared__ float sh_part[4][NCAT];

    const int tid  = threadIdx.x;
    const int lane = tid & 63;
    const int wave = tid >> 6;
    const int ws   = wave & 3;    // window slice
    const int bc   = wave >> 2;   // batch chunk

    if (blockIdx.x == 0 && tid == 0) *cnt = 0u;   // reset pass2 counter

    if (tid < BATCH) {
        int k = de_id[tid];
        sh_de[tid] = k;
        #pragma unroll
        for (int j = 0; j < NCAT; ++j) {
            unsigned long long m = __ballot(k == j);
            if (tid == j) {
                int c = __popcll(m);
                sh_inv[j] = 1.0f / (float)(c > 0 ? c : 1);
            }
        }
    }
    __syncthreads();

    const size_t STR4 = ELEMS / 4;
    // float4 index of this lane's window slot
    const size_t pos4 = (size_t)blockIdx.x * (WIN1 / 4) + ws * 64 + lane;
    const v4f* up4 = (const v4f*)(un) + pos4;

    v4f acc[NCAT];
    #pragma unroll
    for (int j = 0; j < NCAT; ++j) acc[j] = (v4f)0.f;

    // double-buffered prefetch: GRP1 batches in flight
    v4f ub[2][GRP1];
    #pragma unroll
    for (int i = 0; i < GRP1; ++i)
        ub[0][i] = up4[(size_t)(bc * CHUNK1 + i) * STR4];

    #pragma unroll
    for (int g = 0; g < CHUNK1 / GRP1; ++g) {
        const int cur = g & 1;
        const int nxt = cur ^ 1;
        if (g < CHUNK1 / GRP1 - 1) {
            #pragma unroll
            for (int i = 0; i < GRP1; ++i)
                ub[nxt][i] = up4[(size_t)(bc * CHUNK1 + (g + 1) * GRP1 + i) * STR4];
        }
        #pragma unroll
        for (int i = 0; i < GRP1; ++i) {
            const int k = sh_de[bc * CHUNK1 + g * GRP1 + i];
            #pragma unroll
            for (int j = 0; j < NCAT; ++j) {
                float m = (k == j) ? 1.0f : 0.0f;
                acc[j] = vfma(m, ub[cur][i], acc[j]);
            }
        }
    }

    // ---- merge 4 batch-chunks (per slice) into bc==0 (2-round LDS tree) ----
    if (bc >= 2) {
        #pragma unroll
        for (int j = 0; j < NCAT; ++j) sbuf[bc - 2][ws][j][lane] = acc[j];
    }
    __syncthreads();
    if (bc < 2) {
        #pragma unroll
        for (int j = 0; j < NCAT; ++j) acc[j] += sbuf[bc][ws][j][lane];
    }
    __syncthreads();
    if (bc == 1) {
        #pragma unroll
        for (int j = 0; j < NCAT; ++j) sbuf[0][ws][j][lane] = acc[j];
    }
    __syncthreads();
    if (bc == 0) {
        float vals[NCAT];
        #pragma unroll
        for (int j = 0; j < NCAT; ++j) {
            v4f a = acc[j] + sbuf[0][ws][j][lane];

            v4f um, sv;
            um.x = fmaf(a.x, sh_inv[j], EPSV);
            um.y = fmaf(a.y, sh_inv[j], EPSV);
            um.z = fmaf(a.z, sh_inv[j], EPSV);
            um.w = fmaf(a.w, sh_inv[j], EPSV);
            sv.x = 1.0f / um.x;
            sv.y = 1.0f / um.y;
            sv.z = 1.0f / um.z;
            sv.w = 1.0f / um.w;
            ((v4f*)s_buf)[(size_t)j * STR4 + pos4] = sv;

            vals[j] = (a.x + a.y) + (a.z + a.w);
        }
        #pragma unroll
        for (int j = 0; j < NCAT; ++j) {
            float v = vals[j];
            #pragma unroll
            for (int off = 32; off >= 1; off >>= 1)
                v += __shfl_down(v, off, 64);
            if (lane == 0) sh_part[ws][j] = v;
        }
    }
    __syncthreads();
    if (tid < NCAT)
        p1[tid * NBLK1 + blockIdx.x] =
            sh_part[0][tid] + sh_part[1][tid] + sh_part[2][tid] + sh_part[3][tid];
}

// ---------------------------------------------------------------------------
// Pass 2: streaming |clean-restored| and |.|*s over fat contiguous slabs,
// with fused final epilogue in the last-finishing block.
// ---------------------------------------------------------------------------
__global__ __launch_bounds__(256) void pass2_kernel(
    const float* __restrict__ restored,
    const float* __restrict__ clean,
    const int*   __restrict__ de_id,
    const float* __restrict__ s_buf,
    float*       __restrict__ p1,
    float*       __restrict__ p2,
    unsigned*    __restrict__ cnt,
    float*       __restrict__ out)
{
    __shared__ float sred[4][2];
    __shared__ int   sh_last;
    __shared__ int   sh_cat[BATCH];
    __shared__ int   sh_cnt[NCAT];
    __shared__ float sh_acc[3 * NCAT];

    const int tid  = threadIdx.x;
    const int lane = tid & 63;
    const int wave = tid >> 6;

    const int b   = blockIdx.x / NSLAB;
    const int sl  = blockIdx.x % NSLAB;
    const int cat = de_id[b];                 // block-uniform scalar

    const size_t base4 = (size_t)sl * (SLABSZ / 4) + (size_t)wave * (SLABSZ / 16)
                       + (size_t)lane;
    const v4f* cp = (const v4f*)(clean)    + (size_t)b   * (ELEMS / 4) + base4;
    const v4f* rp = (const v4f*)(restored) + (size_t)b   * (ELEMS / 4) + base4;
    const v4f* sp = (const v4f*)(s_buf)    + (size_t)cat * (ELEMS / 4) + base4;

    float ssum = 0.f, asum = 0.f;
    #pragma unroll 16
    for (int it = 0; it < SLABSZ / 16 / 64; ++it) {
        v4f c  = __builtin_nontemporal_load(cp + it * 64);   // read-once
        v4f r  = __builtin_nontemporal_load(rp + it * 64);   // read-once
        v4f sv = sp[it * 64];                                // L2/L3-hot
        float a0 = fabsf(c.x - r.x);
        float a1 = fabsf(c.y - r.y);
        float a2 = fabsf(c.z - r.z);
        float a3 = fabsf(c.w - r.w);
        asum += (a0 + a1) + (a2 + a3);
        ssum = fmaf(a0, sv.x, ssum);
        ssum = fmaf(a1, sv.y, ssum);
        ssum = fmaf(a2, sv.z, ssum);
        ssum = fmaf(a3, sv.w, ssum);
    }

    #pragma unroll
    for (int off = 32; off >= 1; off >>= 1) {
        ssum += __shfl_down(ssum, off, 64);
        asum += __shfl_down(asum, off, 64);
    }
    if (lane == 0) { sred[wave][0] = ssum; sred[wave][1] = asum; }
    __syncthreads();
    if (tid == 0) {
        float s = sred[0][0] + sred[1][0] + sred[2][0] + sred[3][0];
        float a = sred[0][1] + sred[1][1] + sred[2][1] + sred[3][1];
        p2[blockIdx.x]         = s;
        p2[NBLK2 + blockIdx.x] = a;
        __threadfence();                       // publish before counting
        unsigned old = atomicAdd(cnt, 1u);
        sh_last = (old == NBLK2 - 1) ? 1 : 0;
    }
    __syncthreads();
    if (!sh_last) return;

    // ---------------- fused epilogue (single surviving block) ----------------
    if (tid < BATCH) {
        int k = de_id[tid];
        sh_cat[tid] = k;
        #pragma unroll
        for (int j = 0; j < NCAT; ++j) {
            unsigned long long m = __ballot(k == j);
            if (tid == j) sh_cnt[j] = __popcll(m);
        }
    }
    __syncthreads();

    if (wave < 2) {                       // wave0: scaled sums, wave1: abs sums
        const float* src = (wave == 0) ? p2 : p2 + NBLK2;
        float accv[NCAT] = {0.f, 0.f, 0.f, 0.f, 0.f};
        for (int it = 0; it < NBLK2 / 64; ++it) {      // 12 iterations
            int   col = it * 64 + lane;
            float v   = src[col];
            int   c   = sh_cat[col / NSLAB];
            #pragma unroll
            for (int j = 0; j < NCAT; ++j) accv[j] += (c == j) ? v : 0.f;
        }
        #pragma unroll
        for (int j = 0; j < NCAT; ++j) {
            float v = accv[j];
            #pragma unroll
            for (int off = 32; off >= 1; off >>= 1)
                v += __shfl_down(v, off, 64);
            if (lane == 0) sh_acc[wave * NCAT + j] = v;
        }
    } else if (wave == 2) {               // per-cat un sums from p1
        float accv[NCAT] = {0.f, 0.f, 0.f, 0.f, 0.f};
        for (int it = 0; it < NBLK1 / 64; ++it)        // 3 iterations
            #pragma unroll
            for (int j = 0; j < NCAT; ++j)
                accv[j] += p1[j * NBLK1 + it * 64 + lane];
        #pragma unroll
        for (int j = 0; j < NCAT; ++j) {
            float v = accv[j];
            #pragma unroll
            for (int off = 32; off >= 1; off >>= 1)
                v += __shfl_down(v, off, 64);
            if (lane == 0) sh_acc[2 * NCAT + j] = v;
        }
    }
    __syncthreads();

    if (tid == 0) {
        const float Ef = (float)ELEMS;
        float cum_s = 0.f;
        long  cum_c = 0;
        float total = 0.f;
        int   num   = 0;

        float cat_losses[NCAT], old_loss[NCAT], bn[NCAT], unc_l1[NCAT];

        for (int j = 0; j < NCAT; ++j) {
            cum_s += sh_acc[j];
            cum_c += sh_cnt[j];
            float cum_elems = (float)cum_c * Ef;
            float cum_l1    = cum_s / fmaxf(cum_elems, 1.0f);

            bool  ne   = sh_cnt[j] > 0;
            float safe = (float)(ne ? sh_cnt[j] : 1);

            old_loss[j]  = ne ? sh_acc[NCAT + j] / (safe * Ef) : 0.f;
            float un_num = sh_acc[2 * NCAT + j] / (safe * Ef) + EPSV;
            bn[j]        = ne ? 2.0f * logf(un_num) : 0.f;
            unc_l1[j]    = ne ? cum_l1 : 0.f;
            cat_losses[j] = unc_l1[j] + bn[j];
            total += cat_losses[j];
            num   += ne ? 1 : 0;
        }
        total /= (float)num;

        out[0] = total;
        for (int j = 0; j < NCAT; ++j) {
            out[1 + j]  = cat_losses[j];
            out[6 + j]  = old_loss[j];
            out[11 + j] = bn[j];
            out[16 + j] = unc_l1[j];
        }
    }
}

extern "C" void kernel_launch(void* const* d_in, const int* in_sizes, int n_in,
                              void* d_out, int out_size, void* d_ws, size_t ws_size,
                              hipStream_t stream) {
    (void)in_sizes; (void)n_in; (void)out_size; (void)ws_size;
    const float* restored = (const float*)d_in[0];
    const float* clean    = (const float*)d_in[1];
    const int*   de_id    = (const int*)d_in[2];
    const float* un       = (const float*)d_in[3];
    float* out   = (float*)d_out;
    float* ws    = (float*)d_ws;
    float*    s_buf = ws + WS_S;
    float*    p1    = ws + WS_P1;
    float*    p2    = ws + WS_P2;
    unsigned* cnt   = (unsigned*)(ws + WS_CNT);

    pass1_kernel<<<NBLK1, TPB1, 0, stream>>>(un, de_id, s_buf, p1, cnt);
    pass2_kernel<<<NBLK2, 256, 0, stream>>>(restored, clean, de_id, s_buf,
                                            p1, p2, cnt, out);
}

// Round 8
// 164.543 us; speedup vs baseline: 1.2229x; 1.2229x over previous
//
#include <hip/hip_runtime.h>
#include <math.h>

#define NCAT  5
#define BATCH 64
#define ELEMS 196608          // C*H*W = 3*256*256
#define EPSV  1e-6f

// native 4-float vector (works with __builtin_nontemporal_load)
typedef float v4f __attribute__((ext_vector_type(4)));

// ---- pass 1 geometry: 4 KB window per block, 16 waves (4 slices x 4 chunks)
#define WIN1   1024            // floats per block window (4 KB burst per batch)
#define NBLK1  (ELEMS / WIN1)  // 192 blocks
#define TPB1   1024            // 16 waves; ws = wave&3 (slice), bc = wave>>2
#define CHUNK1 16              // batches per chunk-wave
#define GRP1   4               // batches in flight per wave (32 VGPR prefetch)

// ---- pass 2 geometry (streaming over clean/restored/s) ----
#define NSLAB  12              // slabs per batch (64 KB/array/block)
#define SLABSZ (ELEMS / NSLAB) // 16384 positions per slab
#define NBLK2  (BATCH * NSLAB) // 768 blocks

// d_ws layout (floats):
//   s_buf [NCAT][ELEMS]  @ 0        (per-cat scale map 1/un_map)
//   p1    [NCAT][NBLK1]  @ WS_P1    (per-cat un sums)
//   p2    [2][NBLK2]     @ WS_P2    (row0 = scaled sums, row1 = abs sums)
#define WS_S   0
#define WS_P1  (NCAT * ELEMS)
#define WS_P2  (WS_P1 + NCAT * NBLK1)

static __device__ __forceinline__ v4f vfma(float m, v4f a, v4f b) {
    v4f r;
    r.x = fmaf(m, a.x, b.x);
    r.y = fmaf(m, a.y, b.y);
    r.z = fmaf(m, a.z, b.z);
    r.w = fmaf(m, a.w, b.w);
    return r;
}

// ---------------------------------------------------------------------------
// Pass 1: un_sum[cat][pos]; block sweeps a 4 KB window across all 64 batches
// (4 slice-waves in lockstep -> 4 KB DRAM-page runs per batch visit), batch
// dim split over 4 chunk-waves merged via LDS. Emits s = 1/(un_sum*inv+eps)
// and per-cat un sums. 192 blocks x 16 waves = 3072 waves (same as round 5).
// ---------------------------------------------------------------------------
__global__ __launch_bounds__(TPB1) void pass1_kernel(
    const float* __restrict__ un,
    const int*   __restrict__ de_id,
    float*       __restrict__ s_buf,
    float*       __restrict__ p1)
{
    __shared__ int   sh_de[BATCH];
    __shared__ float sh_inv[NCAT];
    __shared__ v4f   sbuf[2][4][NCAT][64];   // [slot][slice][cat][lane] 40 KB
    __shared__ float sh_part[4][NCAT];

    const int tid  = threadIdx.x;
    const int lane = tid & 63;
    const int wave = tid >> 6;
    const int ws   = wave & 3;    // window slice
    const int bc   = wave >> 2;   // batch chunk

    if (tid < BATCH) {
        int k = de_id[tid];
        sh_de[tid] = k;
        #pragma unroll
        for (int j = 0; j < NCAT; ++j) {
            unsigned long long m = __ballot(k == j);
            if (tid == j) {
                int c = __popcll(m);
                sh_inv[j] = 1.0f / (float)(c > 0 ? c : 1);
            }
        }
    }
    __syncthreads();

    const size_t STR4 = ELEMS / 4;
    // float4 index of this lane's window slot
    const size_t pos4 = (size_t)blockIdx.x * (WIN1 / 4) + ws * 64 + lane;
    const v4f* up4 = (const v4f*)(un) + pos4;

    v4f acc[NCAT];
    #pragma unroll
    for (int j = 0; j < NCAT; ++j) acc[j] = (v4f)0.f;

    // double-buffered prefetch: GRP1 batches in flight
    v4f ub[2][GRP1];
    #pragma unroll
    for (int i = 0; i < GRP1; ++i)
        ub[0][i] = up4[(size_t)(bc * CHUNK1 + i) * STR4];

    #pragma unroll
    for (int g = 0; g < CHUNK1 / GRP1; ++g) {
        const int cur = g & 1;
        const int nxt = cur ^ 1;
        if (g < CHUNK1 / GRP1 - 1) {
            #pragma unroll
            for (int i = 0; i < GRP1; ++i)
                ub[nxt][i] = up4[(size_t)(bc * CHUNK1 + (g + 1) * GRP1 + i) * STR4];
        }
        #pragma unroll
        for (int i = 0; i < GRP1; ++i) {
            const int k = sh_de[bc * CHUNK1 + g * GRP1 + i];
            #pragma unroll
            for (int j = 0; j < NCAT; ++j) {
                float m = (k == j) ? 1.0f : 0.0f;
                acc[j] = vfma(m, ub[cur][i], acc[j]);
            }
        }
    }

    // ---- merge 4 batch-chunks (per slice) into bc==0 (2-round LDS tree) ----
    if (bc >= 2) {
        #pragma unroll
        for (int j = 0; j < NCAT; ++j) sbuf[bc - 2][ws][j][lane] = acc[j];
    }
    __syncthreads();
    if (bc < 2) {
        #pragma unroll
        for (int j = 0; j < NCAT; ++j) acc[j] += sbuf[bc][ws][j][lane];
    }
    __syncthreads();
    if (bc == 1) {
        #pragma unroll
        for (int j = 0; j < NCAT; ++j) sbuf[0][ws][j][lane] = acc[j];
    }
    __syncthreads();
    if (bc == 0) {
        float vals[NCAT];
        #pragma unroll
        for (int j = 0; j < NCAT; ++j) {
            v4f a = acc[j] + sbuf[0][ws][j][lane];

            v4f um, sv;
            um.x = fmaf(a.x, sh_inv[j], EPSV);
            um.y = fmaf(a.y, sh_inv[j], EPSV);
            um.z = fmaf(a.z, sh_inv[j], EPSV);
            um.w = fmaf(a.w, sh_inv[j], EPSV);
            sv.x = 1.0f / um.x;
            sv.y = 1.0f / um.y;
            sv.z = 1.0f / um.z;
            sv.w = 1.0f / um.w;
            ((v4f*)s_buf)[(size_t)j * STR4 + pos4] = sv;

            vals[j] = (a.x + a.y) + (a.z + a.w);
        }
        #pragma unroll
        for (int j = 0; j < NCAT; ++j) {
            float v = vals[j];
            #pragma unroll
            for (int off = 32; off >= 1; off >>= 1)
                v += __shfl_down(v, off, 64);
            if (lane == 0) sh_part[ws][j] = v;
        }
    }
    __syncthreads();
    if (tid < NCAT)
        p1[tid * NBLK1 + blockIdx.x] =
            sh_part[0][tid] + sh_part[1][tid] + sh_part[2][tid] + sh_part[3][tid];
}

// ---------------------------------------------------------------------------
// Pass 2 (round-5 proven version): streaming |clean-restored| and |.|*s over
// fat contiguous slabs.
// ---------------------------------------------------------------------------
__global__ __launch_bounds__(256) void pass2_kernel(
    const float* __restrict__ restored,
    const float* __restrict__ clean,
    const int*   __restrict__ de_id,
    const float* __restrict__ s_buf,
    float*       __restrict__ p2)
{
    __shared__ float sred[4][2];

    const int tid  = threadIdx.x;
    const int lane = tid & 63;
    const int wave = tid >> 6;

    const int b   = blockIdx.x / NSLAB;
    const int sl  = blockIdx.x % NSLAB;
    const int cat = de_id[b];                 // block-uniform scalar

    const size_t base4 = (size_t)sl * (SLABSZ / 4) + (size_t)wave * (SLABSZ / 16)
                       + (size_t)lane;
    const v4f* cp = (const v4f*)(clean)    + (size_t)b   * (ELEMS / 4) + base4;
    const v4f* rp = (const v4f*)(restored) + (size_t)b   * (ELEMS / 4) + base4;
    const v4f* sp = (const v4f*)(s_buf)    + (size_t)cat * (ELEMS / 4) + base4;

    float ssum = 0.f, asum = 0.f;
    #pragma unroll 16
    for (int it = 0; it < SLABSZ / 16 / 64; ++it) {
        v4f c  = __builtin_nontemporal_load(cp + it * 64);   // read-once
        v4f r  = __builtin_nontemporal_load(rp + it * 64);   // read-once
        v4f sv = sp[it * 64];                                // L2/L3-hot
        float a0 = fabsf(c.x - r.x);
        float a1 = fabsf(c.y - r.y);
        float a2 = fabsf(c.z - r.z);
        float a3 = fabsf(c.w - r.w);
        asum += (a0 + a1) + (a2 + a3);
        ssum = fmaf(a0, sv.x, ssum);
        ssum = fmaf(a1, sv.y, ssum);
        ssum = fmaf(a2, sv.z, ssum);
        ssum = fmaf(a3, sv.w, ssum);
    }

    #pragma unroll
    for (int off = 32; off >= 1; off >>= 1) {
        ssum += __shfl_down(ssum, off, 64);
        asum += __shfl_down(asum, off, 64);
    }
    if (lane == 0) { sred[wave][0] = ssum; sred[wave][1] = asum; }
    __syncthreads();
    if (tid == 0) {
        float s = sred[0][0] + sred[1][0] + sred[2][0] + sred[3][0];
        float a = sred[0][1] + sred[1][1] + sred[2][1] + sred[3][1];
        p2[blockIdx.x]         = s;
        p2[NBLK2 + blockIdx.x] = a;
    }
}

// ---------------------------------------------------------------------------
// Epilogue (round-5 proven version): gather p2 by category, reduce p1,
// final 21-output math.
// ---------------------------------------------------------------------------
__global__ __launch_bounds__(1024) void epilogue_kernel(
    const int*   __restrict__ de_id,
    const float* __restrict__ p1,
    const float* __restrict__ p2,
    float*       __restrict__ out)
{
    __shared__ int   sh_cnt[NCAT];
    __shared__ int   sh_cat[BATCH];
    __shared__ float sh_acc[3 * NCAT];

    const int tid  = threadIdx.x;
    const int lane = tid & 63;
    const int wave = tid >> 6;

    if (tid < BATCH) {
        int k = de_id[tid];
        sh_cat[tid] = k;
        #pragma unroll
        for (int j = 0; j < NCAT; ++j) {
            unsigned long long m = __ballot(k == j);
            if (tid == j) sh_cnt[j] = __popcll(m);
        }
    }
    __syncthreads();

    float v = 0.f;
    if (wave < 5) {                       // scaled sums per cat
        for (int it = 0; it < NBLK2 / 64; ++it) {
            int col = it * 64 + lane;
            v += (sh_cat[col / NSLAB] == wave) ? p2[col] : 0.f;
        }
    } else if (wave < 10) {               // abs sums per cat
        const int j = wave - 5;
        for (int it = 0; it < NBLK2 / 64; ++it) {
            int col = it * 64 + lane;
            v += (sh_cat[col / NSLAB] == j) ? p2[NBLK2 + col] : 0.f;
        }
    } else if (wave < 15) {               // un sums per cat
        const int j = wave - 10;
        for (int it = 0; it < NBLK1 / 64; ++it)
            v += p1[j * NBLK1 + it * 64 + lane];
    }
    #pragma unroll
    for (int off = 32; off >= 1; off >>= 1)
        v += __shfl_down(v, off, 64);
    if (lane == 0 && wave < 15) sh_acc[wave] = v;
    __syncthreads();

    if (tid == 0) {
        const float Ef = (float)ELEMS;
        float cum_s = 0.f;
        long  cum_c = 0;
        float total = 0.f;
        int   num   = 0;

        float cat_losses[NCAT], old_loss[NCAT], bn[NCAT], unc_l1[NCAT];

        for (int j = 0; j < NCAT; ++j) {
            cum_s += sh_acc[j];
            cum_c += sh_cnt[j];
            float cum_elems = (float)cum_c * Ef;
            float cum_l1    = cum_s / fmaxf(cum_elems, 1.0f);

            bool  ne   = sh_cnt[j] > 0;
            float safe = (float)(ne ? sh_cnt[j] : 1);

            old_loss[j]  = ne ? sh_acc[NCAT + j] / (safe * Ef) : 0.f;
            float un_num = sh_acc[2 * NCAT + j] / (safe * Ef) + EPSV;
            bn[j]        = ne ? 2.0f * logf(un_num) : 0.f;
            unc_l1[j]    = ne ? cum_l1 : 0.f;
            cat_losses[j] = unc_l1[j] + bn[j];
            total += cat_losses[j];
            num   += ne ? 1 : 0;
        }
        total /= (float)num;

        out[0] = total;
        for (int j = 0; j < NCAT; ++j) {
            out[1 + j]  = cat_losses[j];
            out[6 + j]  = old_loss[j];
            out[11 + j] = bn[j];
            out[16 + j] = unc_l1[j];
        }
    }
}

extern "C" void kernel_launch(void* const* d_in, const int* in_sizes, int n_in,
                              void* d_out, int out_size, void* d_ws, size_t ws_size,
                              hipStream_t stream) {
    (void)in_sizes; (void)n_in; (void)out_size; (void)ws_size;
    const float* restored = (const float*)d_in[0];
    const float* clean    = (const float*)d_in[1];
    const int*   de_id    = (const int*)d_in[2];
    const float* un       = (const float*)d_in[3];
    float* out   = (float*)d_out;
    float* ws    = (float*)d_ws;
    float* s_buf = ws + WS_S;
    float* p1    = ws + WS_P1;
    float* p2    = ws + WS_P2;

    pass1_kernel<<<NBLK1, TPB1, 0, stream>>>(un, de_id, s_buf, p1);
    pass2_kernel<<<NBLK2, 256, 0, stream>>>(restored, clean, de_id, s_buf, p2);
    epilogue_kernel<<<1, 1024, 0, stream>>>(de_id, p1, p2, out);
}

// Round 9
// 162.614 us; speedup vs baseline: 1.2374x; 1.0119x over previous
//
#include <hip/hip_runtime.h>
#include <math.h>

#define NCAT  5
#define BATCH 64
#define ELEMS 196608          // C*H*W = 3*256*256
#define EPSV  1e-6f

// native 4-float vector (works with __builtin_nontemporal_load)
typedef float v4f __attribute__((ext_vector_type(4)));

// ---- pass 1 geometry: category-grouped streaming ----
// block = (cat, slab): reads the ~N_c batches of its category at one
// contiguous 12 KB slab each (sequential runs, pass2-style access class).
#define NSLAB1 64              // slabs per category
#define SLAB1  (ELEMS / NSLAB1) // 3072 floats = 12 KB per slab
#define NP1    NSLAB1           // p1 row length (per-cat partial count)
#define NBLKP1 (NCAT * NSLAB1)  // 320 blocks

// ---- pass 2 geometry (streaming over clean/restored/s, r5-proven) ----
#define NSLAB  12              // slabs per batch (64 KB/array/block)
#define SLABSZ (ELEMS / NSLAB) // 16384 positions per slab
#define NBLK2  (BATCH * NSLAB) // 768 blocks

// d_ws layout (floats):
//   s_buf [NCAT][ELEMS]  @ 0        (per-cat scale map 1/un_map)
//   p1    [NCAT][NP1]    @ WS_P1    (per-cat un sums)
//   p2    [2][NBLK2]     @ WS_P2    (row0 = scaled sums, row1 = abs sums)
#define WS_S   0
#define WS_P1  (NCAT * ELEMS)
#define WS_P2  (WS_P1 + NCAT * NP1)

// ---------------------------------------------------------------------------
// Pass 1 (category-grouped streaming): block (c, sl) sums un[b][slab sl] over
// batches b with de_id[b]==c — each read a contiguous 12 KB run. Emits
// s = 1/(un_sum*inv+eps) for its (cat, slab) and a per-(cat,slab) un partial.
// ---------------------------------------------------------------------------
__global__ __launch_bounds__(256) void pass1_kernel(
    const float* __restrict__ un,
    const int*   __restrict__ de_id,
    float*       __restrict__ s_buf,
    float*       __restrict__ p1)
{
    __shared__ int   sh_list[BATCH];
    __shared__ int   sh_n;
    __shared__ float sh_inv;
    __shared__ float sred[4];

    const int tid  = threadIdx.x;
    const int lane = tid & 63;
    const int wave = tid >> 6;

    const int c  = blockIdx.x / NSLAB1;   // category
    const int sl = blockIdx.x % NSLAB1;   // slab

    // wave 0: ballot-compact the list of batches in category c
    if (tid < BATCH) {
        bool match = (de_id[tid] == c);
        unsigned long long mask = __ballot(match);
        if (match)
            sh_list[__popcll(mask & ((1ull << tid) - 1ull))] = tid;
        if (tid == 0) {
            int n = __popcll(mask);
            sh_n   = n;
            sh_inv = 1.0f / (float)(n > 0 ? n : 1);
        }
    }
    __syncthreads();
    const int   n   = sh_n;
    const float inv = sh_inv;

    const size_t STR4 = ELEMS / 4;
    // v4f offset of this lane inside the slab (3 v4f per thread, stride 64)
    const size_t off4 = (size_t)sl * (SLAB1 / 4) + (size_t)wave * (SLAB1 / 16)
                      + (size_t)lane;
    const v4f* up = (const v4f*)(un) + off4;

    v4f acc0 = (v4f)0.f, acc1 = (v4f)0.f, acc2 = (v4f)0.f;

    // 2-deep prefetch ring, all register indices static (named buffers)
    v4f a0 = (v4f)0.f, a1 = (v4f)0.f, a2 = (v4f)0.f;
    v4f b0 = (v4f)0.f, b1 = (v4f)0.f, b2 = (v4f)0.f;

    if (n > 0) {
        const size_t o = (size_t)sh_list[0] * STR4;
        a0 = up[o]; a1 = up[o + 64]; a2 = up[o + 128];
    }
    for (int i = 0; i < n; i += 2) {
        if (i + 1 < n) {
            const size_t o = (size_t)sh_list[i + 1] * STR4;
            b0 = up[o]; b1 = up[o + 64]; b2 = up[o + 128];
        }
        acc0 += a0; acc1 += a1; acc2 += a2;
        if (i + 2 < n) {
            const size_t o = (size_t)sh_list[i + 2] * STR4;
            a0 = up[o]; a1 = up[o + 64]; a2 = up[o + 128];
        }
        if (i + 1 < n) { acc0 += b0; acc1 += b1; acc2 += b2; }
    }

    // s = 1/(un_sum*inv + eps), written sequentially for this (cat, slab)
    v4f* sp = (v4f*)(s_buf) + (size_t)c * STR4 + off4;
    v4f um, sv;
    um.x = fmaf(acc0.x, inv, EPSV); um.y = fmaf(acc0.y, inv, EPSV);
    um.z = fmaf(acc0.z, inv, EPSV); um.w = fmaf(acc0.w, inv, EPSV);
    sv.x = 1.0f/um.x; sv.y = 1.0f/um.y; sv.z = 1.0f/um.z; sv.w = 1.0f/um.w;
    sp[0] = sv;
    um.x = fmaf(acc1.x, inv, EPSV); um.y = fmaf(acc1.y, inv, EPSV);
    um.z = fmaf(acc1.z, inv, EPSV); um.w = fmaf(acc1.w, inv, EPSV);
    sv.x = 1.0f/um.x; sv.y = 1.0f/um.y; sv.z = 1.0f/um.z; sv.w = 1.0f/um.w;
    sp[64] = sv;
    um.x = fmaf(acc2.x, inv, EPSV); um.y = fmaf(acc2.y, inv, EPSV);
    um.z = fmaf(acc2.z, inv, EPSV); um.w = fmaf(acc2.w, inv, EPSV);
    sv.x = 1.0f/um.x; sv.y = 1.0f/um.y; sv.z = 1.0f/um.z; sv.w = 1.0f/um.w;
    sp[128] = sv;

    // per-(cat,slab) un partial: sum all components, block-reduce
    v4f t = acc0 + acc1 + acc2;
    float v = (t.x + t.y) + (t.z + t.w);
    #pragma unroll
    for (int off = 32; off >= 1; off >>= 1)
        v += __shfl_down(v, off, 64);
    if (lane == 0) sred[wave] = v;
    __syncthreads();
    if (tid == 0)
        p1[c * NP1 + sl] = sred[0] + sred[1] + sred[2] + sred[3];
}

// ---------------------------------------------------------------------------
// Pass 2 (round-5 proven): streaming |clean-restored| and |.|*s over fat
// contiguous slabs.
// ---------------------------------------------------------------------------
__global__ __launch_bounds__(256) void pass2_kernel(
    const float* __restrict__ restored,
    const float* __restrict__ clean,
    const int*   __restrict__ de_id,
    const float* __restrict__ s_buf,
    float*       __restrict__ p2)
{
    __shared__ float sred[4][2];

    const int tid  = threadIdx.x;
    const int lane = tid & 63;
    const int wave = tid >> 6;

    const int b   = blockIdx.x / NSLAB;
    const int sl  = blockIdx.x % NSLAB;
    const int cat = de_id[b];                 // block-uniform scalar

    const size_t base4 = (size_t)sl * (SLABSZ / 4) + (size_t)wave * (SLABSZ / 16)
                       + (size_t)lane;
    const v4f* cp = (const v4f*)(clean)    + (size_t)b   * (ELEMS / 4) + base4;
    const v4f* rp = (const v4f*)(restored) + (size_t)b   * (ELEMS / 4) + base4;
    const v4f* sp = (const v4f*)(s_buf)    + (size_t)cat * (ELEMS / 4) + base4;

    float ssum = 0.f, asum = 0.f;
    #pragma unroll 16
    for (int it = 0; it < SLABSZ / 16 / 64; ++it) {
        v4f c  = __builtin_nontemporal_load(cp + it * 64);   // read-once
        v4f r  = __builtin_nontemporal_load(rp + it * 64);   // read-once
        v4f sv = sp[it * 64];                                // L2/L3-hot
        float a0 = fabsf(c.x - r.x);
        float a1 = fabsf(c.y - r.y);
        float a2 = fabsf(c.z - r.z);
        float a3 = fabsf(c.w - r.w);
        asum += (a0 + a1) + (a2 + a3);
        ssum = fmaf(a0, sv.x, ssum);
        ssum = fmaf(a1, sv.y, ssum);
        ssum = fmaf(a2, sv.z, ssum);
        ssum = fmaf(a3, sv.w, ssum);
    }

    #pragma unroll
    for (int off = 32; off >= 1; off >>= 1) {
        ssum += __shfl_down(ssum, off, 64);
        asum += __shfl_down(asum, off, 64);
    }
    if (lane == 0) { sred[wave][0] = ssum; sred[wave][1] = asum; }
    __syncthreads();
    if (tid == 0) {
        float s = sred[0][0] + sred[1][0] + sred[2][0] + sred[3][0];
        float a = sred[0][1] + sred[1][1] + sred[2][1] + sred[3][1];
        p2[blockIdx.x]         = s;
        p2[NBLK2 + blockIdx.x] = a;
    }
}

// ---------------------------------------------------------------------------
// Epilogue: gather p2 by category, reduce p1, final 21-output math.
// ---------------------------------------------------------------------------
__global__ __launch_bounds__(1024) void epilogue_kernel(
    const int*   __restrict__ de_id,
    const float* __restrict__ p1,
    const float* __restrict__ p2,
    float*       __restrict__ out)
{
    __shared__ int   sh_cnt[NCAT];
    __shared__ int   sh_cat[BATCH];
    __shared__ float sh_acc[3 * NCAT];

    const int tid  = threadIdx.x;
    const int lane = tid & 63;
    const int wave = tid >> 6;

    if (tid < BATCH) {
        int k = de_id[tid];
        sh_cat[tid] = k;
        #pragma unroll
        for (int j = 0; j < NCAT; ++j) {
            unsigned long long m = __ballot(k == j);
            if (tid == j) sh_cnt[j] = __popcll(m);
        }
    }
    __syncthreads();

    float v = 0.f;
    if (wave < 5) {                       // scaled sums per cat
        for (int it = 0; it < NBLK2 / 64; ++it) {
            int col = it * 64 + lane;
            v += (sh_cat[col / NSLAB] == wave) ? p2[col] : 0.f;
        }
    } else if (wave < 10) {               // abs sums per cat
        const int j = wave - 5;
        for (int it = 0; it < NBLK2 / 64; ++it) {
            int col = it * 64 + lane;
            v += (sh_cat[col / NSLAB] == j) ? p2[NBLK2 + col] : 0.f;
        }
    } else if (wave < 15) {               // un sums per cat
        const int j = wave - 10;
        #pragma unroll
        for (int it = 0; it < NP1 / 64; ++it)
            v += p1[j * NP1 + it * 64 + lane];
    }
    #pragma unroll
    for (int off = 32; off >= 1; off >>= 1)
        v += __shfl_down(v, off, 64);
    if (lane == 0 && wave < 15) sh_acc[wave] = v;
    __syncthreads();

    if (tid == 0) {
        const float Ef = (float)ELEMS;
        float cum_s = 0.f;
        long  cum_c = 0;
        float total = 0.f;
        int   num   = 0;

        float cat_losses[NCAT], old_loss[NCAT], bn[NCAT], unc_l1[NCAT];

        for (int j = 0; j < NCAT; ++j) {
            cum_s += sh_acc[j];
            cum_c += sh_cnt[j];
            float cum_elems = (float)cum_c * Ef;
            float cum_l1    = cum_s / fmaxf(cum_elems, 1.0f);

            bool  ne   = sh_cnt[j] > 0;
            float safe = (float)(ne ? sh_cnt[j] : 1);

            old_loss[j]  = ne ? sh_acc[NCAT + j] / (safe * Ef) : 0.f;
            float un_num = sh_acc[2 * NCAT + j] / (safe * Ef) + EPSV;
            bn[j]        = ne ? 2.0f * logf(un_num) : 0.f;
            unc_l1[j]    = ne ? cum_l1 : 0.f;
            cat_losses[j] = unc_l1[j] + bn[j];
            total += cat_losses[j];
            num   += ne ? 1 : 0;
        }
        total /= (float)num;

        out[0] = total;
        for (int j = 0; j < NCAT; ++j) {
            out[1 + j]  = cat_losses[j];
            out[6 + j]  = old_loss[j];
            out[11 + j] = bn[j];
            out[16 + j] = unc_l1[j];
        }
    }
}

extern "C" void kernel_launch(void* const* d_in, const int* in_sizes, int n_in,
                              void* d_out, int out_size, void* d_ws, size_t ws_size,
                              hipStream_t stream) {
    (void)in_sizes; (void)n_in; (void)out_size; (void)ws_size;
    const float* restored = (const float*)d_in[0];
    const float* clean    = (const float*)d_in[1];
    const int*   de_id    = (const int*)d_in[2];
    const float* un       = (const float*)d_in[3];
    float* out   = (float*)d_out;
    float* ws    = (float*)d_ws;
    float* s_buf = ws + WS_S;
    float* p1    = ws + WS_P1;
    float* p2    = ws + WS_P2;

    pass1_kernel<<<NBLKP1, 256, 0, stream>>>(un, de_id, s_buf, p1);
    pass2_kernel<<<NBLK2, 256, 0, stream>>>(restored, clean, de_id, s_buf, p2);
    epilogue_kernel<<<1, 1024, 0, stream>>>(de_id, p1, p2, out);
}